// Round 10
// baseline (51.252 us; speedup 1.0000x reference)
//
#include <hip/hip_runtime.h>
#include <math.h>

#define NN 4096
#define INDIM 45
#define HH 44
#define NHEAD 4
#define HD 11
#define NEDGE 131072
#define CAP 128            // compaction capacity (deg ~ Poisson(32)+diag)
#define CAPST 68           // staged-KV column capacity (fast path handles deg<=64)
#define MASKW (NN / 64)
#define NPB 8              // nodes per block in proj_zero

__device__ __forceinline__ float wsum64(float v) {
    #pragma unroll
    for (int i = 32; i > 0; i >>= 1) v += __shfl_xor(v, i, 64);
    return v;
}
__device__ __forceinline__ float wmax64(float v) {
    #pragma unroll
    for (int i = 32; i > 0; i >>= 1) v = fmaxf(v, __shfl_xor(v, i, 64));
    return v;
}

// ---------------- Kernel 1: zero mask + fused input/QKV projection ----------------
// Q layout: [n][h][12] (pad 1), KV layout: [n][h][24] (K at +0..10, V at +12..22).
__global__ __launch_bounds__(256)
void proj_zero(const float* __restrict__ nf,
               const float* __restrict__ Wp, const float* __restrict__ bp,
               const float* __restrict__ Wq, const float* __restrict__ bq,
               const float* __restrict__ Wk, const float* __restrict__ bk,
               const float* __restrict__ Wv, const float* __restrict__ bv,
               unsigned long long* __restrict__ mask,
               float* __restrict__ Qp, float* __restrict__ KVp) {
    const int tid = threadIdx.x;
    const int gsz = gridDim.x * 256;
    for (int i = blockIdx.x * 256 + tid; i < NN * MASKW; i += gsz) mask[i] = 0ull;

    __shared__ float xs[NPB][HH];
    const int n0 = blockIdx.x * NPB;
    for (int idx = tid; idx < NPB * HH; idx += 256) {
        int nl = idx / HH, j = idx - nl * HH;
        const float* row = nf + (size_t)(n0 + nl) * INDIM;
        float a = bp[j];
        #pragma unroll
        for (int k = 0; k < INDIM; ++k) a += row[k] * Wp[k * HH + j];
        xs[nl][j] = a;
    }
    __syncthreads();
    for (int idx = tid; idx < NPB * HH; idx += 256) {
        int nl = idx / HH, j = idx - nl * HH;
        const float* row = xs[nl];
        float aq = bq[j], ak = bk[j], av = bv[j];
        #pragma unroll
        for (int k = 0; k < HH; ++k) {
            float xv = row[k];
            aq += xv * Wq[k * HH + j];
            ak += xv * Wk[k * HH + j];
            av += xv * Wv[k * HH + j];
        }
        int h = j / HD, d = j - h * HD;
        size_t nh = (size_t)(n0 + nl) * NHEAD + h;
        Qp[nh * 12 + d]       = aq;
        KVp[nh * 24 + d]      = ak;
        KVp[nh * 24 + 12 + d] = av;
    }
}

// ---------------- Kernel 2: scatter edges (diagonal folded into attn) ----------------
__global__ __launch_bounds__(256)
void build_mask(const int* __restrict__ ei, unsigned long long* __restrict__ mask) {
    int i = blockIdx.x * blockDim.x + threadIdx.x;
    if (i < NEDGE) {
        int r = ei[i];          // query
        int c = ei[NEDGE + i];  // key
        atomicOr(&mask[(size_t)r * MASKW + (c >> 6)], 1ull << (c & 63));
    }
}

// ---------------- Kernel 3: sparse attention + fused output projection ----------------
// Block = one query row, wave h = head h.
//  1) every wave redundantly compacts the mask row into its own LDS segment
//     (no barrier needed; identical deterministic values)
//  2) ALL 256 threads cooperatively stage the ~deg needed KV rows into a
//     transposed LDS layout with COALESCED loads (consecutive threads read
//     consecutive 16B of the same column) — replaces the 4x-redundant per-lane
//     scatter (6 instrs x 64 random cache lines each) that serialized in L1.
//     Wave 0 stages the temporal bias once.
//  3) one barrier; direct softmax from LDS (conflict-free 16B-stride reads).
__global__ __launch_bounds__(256, 4)
void attn_out(const float* __restrict__ Qp, const float* __restrict__ KVp,
              const float* __restrict__ temporal,
              const unsigned long long* __restrict__ mask,
              const float* __restrict__ Wo, const float* __restrict__ bo,
              float* __restrict__ out) {
    const int tid = threadIdx.x;
    const int lane = tid & 63;
    const int h = tid >> 6;
    const int n = blockIdx.x;
    const float scale = 0.30151134457776363f;  // 1/sqrt(11)
    const float tbmul = 9.99990000099999f;     // 1/(0.1+1e-6)

    __shared__ int cols_s[NHEAD][CAP];
    __shared__ float4 kv_s[24 * CAPST];        // kv_s[fi*CAPST + col]
    __shared__ float tb_s[CAPST];
    __shared__ float att_s[HH];

    // --- per-wave redundant compaction (edges + diagonal) ---
    unsigned long long w = mask[(size_t)n * MASKW + lane];
    if (lane == (n >> 6)) w |= 1ull << (n & 63);
    int c = __popcll(w);
    int inc = c;
    #pragma unroll
    for (int i = 1; i < 64; i <<= 1) {
        int v = __shfl_up(inc, i, 64);
        if (lane >= i) inc += v;
    }
    int off = inc - c;                 // exclusive prefix
    int deg = __shfl(inc, 63, 64);
    if (deg > CAP) deg = CAP;
    while (w) {
        int b = __builtin_ctzll(w);
        w &= w - 1;
        if (off < CAP) cols_s[h][off] = lane * 64 + b;
        ++off;
    }

    const int degc = deg <= 64 ? deg : 64;

    // --- cooperative coalesced KV staging (own wave's cols copy -> no barrier yet) ---
    const float4* KVp4 = (const float4*)KVp;
    for (int idx = tid; idx < 24 * degc; idx += 256) {
        int cc = idx / 24, fi = idx - cc * 24;
        int col = cols_s[h][cc];
        kv_s[fi * CAPST + cc] = KVp4[(size_t)col * 24 + fi];
    }
    // wave 0: temporal bias, staged once per row
    if (h == 0) {
        tb_s[lane < CAPST ? lane : 0] = 0.f;   // harmless init for pad slots
        if (lane < degc)
            tb_s[lane] = sqrtf(temporal[((size_t)n * NN + cols_s[0][lane]) * 2] * tbmul);
    }
    __syncthreads();

    const float4* qp4 = (const float4*)(Qp + ((size_t)n * NHEAD + h) * 12);
    float4 q0 = qp4[0], q1 = qp4[1], q2 = qp4[2];

    if (deg <= 64) {
        // ---- fast path: single chunk, direct softmax, K/V from LDS ----
        const bool act = lane < deg;
        const int ld = act ? lane : 0;         // clamped -> reads valid staged data
        float4 a0 = kv_s[(h * 6 + 0) * CAPST + ld];
        float4 a1 = kv_s[(h * 6 + 1) * CAPST + ld];
        float4 a2 = kv_s[(h * 6 + 2) * CAPST + ld];
        float4 b0 = kv_s[(h * 6 + 3) * CAPST + ld];
        float4 b1 = kv_s[(h * 6 + 4) * CAPST + ld];
        float4 b2 = kv_s[(h * 6 + 5) * CAPST + ld];
        float s = q0.x*a0.x + q0.y*a0.y + q0.z*a0.z + q0.w*a0.w
                + q1.x*a1.x + q1.y*a1.y + q1.z*a1.z + q1.w*a1.w
                + q2.x*a2.x + q2.y*a2.y + q2.z*a2.z;
        s = act ? s * scale - tb_s[ld] : -INFINITY;
        float M = wmax64(s);
        float p = act ? __expf(s - M) : 0.f;
        float L = wsum64(p);
        float inv = 1.f / L;
        float vv[12] = {b0.x,b0.y,b0.z,b0.w, b1.x,b1.y,b1.z,b1.w, b2.x,b2.y,b2.z,b2.w};
        #pragma unroll
        for (int d = 0; d < HD; ++d) {
            float o = wsum64(p * vv[d]);
            if (lane == d) att_s[h * HD + d] = o * inv;
        }
    } else {
        // ---- rare fallback (deg>64): online softmax straight from global ----
        float mcur = -INFINITY, lsum = 0.f, oacc[HD];
        #pragma unroll
        for (int d = 0; d < HD; ++d) oacc[d] = 0.f;
        for (int base = 0; base < deg; base += 64) {
            const int jj = base + lane;
            const bool act = jj < deg;
            const int col = act ? cols_s[h][jj] : 0;
            float t = temporal[((size_t)n * NN + col) * 2];
            const float4* kv4 = (const float4*)(KVp + ((size_t)col * NHEAD + h) * 24);
            float4 a0 = kv4[0], a1 = kv4[1], a2 = kv4[2];
            float4 b0 = kv4[3], b1 = kv4[4], b2 = kv4[5];
            float s = q0.x*a0.x + q0.y*a0.y + q0.z*a0.z + q0.w*a0.w
                    + q1.x*a1.x + q1.y*a1.y + q1.z*a1.z + q1.w*a1.w
                    + q2.x*a2.x + q2.y*a2.y + q2.z*a2.z;
            float vv[12] = {b0.x,b0.y,b0.z,b0.w, b1.x,b1.y,b1.z,b1.w, b2.x,b2.y,b2.z,b2.w};
            if (act) {
                s = s * scale - sqrtf(t * tbmul);
                if (s > mcur) {
                    float f = __expf(mcur - s);
                    lsum *= f;
                    #pragma unroll
                    for (int d = 0; d < HD; ++d) oacc[d] *= f;
                    mcur = s;
                }
                float p = __expf(s - mcur);
                lsum += p;
                #pragma unroll
                for (int d = 0; d < HD; ++d) oacc[d] += p * vv[d];
            }
        }
        float M = wmax64(mcur);
        float sc = (mcur == -INFINITY) ? 0.f : __expf(mcur - M);
        float L = wsum64(lsum * sc);
        float inv = 1.f / L;
        #pragma unroll
        for (int d = 0; d < HD; ++d) {
            float o = wsum64(oacc[d] * sc);
            if (lane == d) att_s[h * HD + d] = o * inv;
        }
    }
    __syncthreads();

    if (tid < HH) {
        float a = bo[tid];
        #pragma unroll
        for (int k = 0; k < HH; ++k) a += att_s[k] * Wo[k * HH + tid];
        out[(size_t)n * HH + tid] = a;
    }
}

extern "C" void kernel_launch(void* const* d_in, const int* in_sizes, int n_in,
                              void* d_out, int out_size, void* d_ws, size_t ws_size,
                              hipStream_t stream) {
    const float* nf       = (const float*)d_in[0];
    const int*   ei       = (const int*)d_in[1];
    const float* temporal = (const float*)d_in[2];
    const float* Wp = (const float*)d_in[3];
    const float* bp = (const float*)d_in[4];
    const float* Wq = (const float*)d_in[5];
    const float* bq = (const float*)d_in[6];
    const float* Wk = (const float*)d_in[7];
    const float* bk = (const float*)d_in[8];
    const float* Wv = (const float*)d_in[9];
    const float* bv = (const float*)d_in[10];
    const float* Wo = (const float*)d_in[11];
    const float* bo = (const float*)d_in[12];
    float* outp = (float*)d_out;

    char* ws = (char*)d_ws;
    unsigned long long* mask = (unsigned long long*)ws;        // 2 MB
    float* Qp  = (float*)(ws + (2u << 20));                    // NN*4*12 floats
    float* KVp = Qp + (size_t)NN * NHEAD * 12;                 // NN*4*24 floats

    proj_zero<<<NN / NPB, 256, 0, stream>>>(nf, Wp, bp, Wq, bq, Wk, bk, Wv, bv,
                                            mask, Qp, KVp);
    build_mask<<<(NEDGE + 255) / 256, 256, 0, stream>>>(ei, mask);
    attn_out<<<NN, 256, 0, stream>>>(Qp, KVp, temporal, mask, Wo, bo, outp);
}

// Round 11
// 38.072 us; speedup vs baseline: 1.3462x; 1.3462x over previous
//
#include <hip/hip_runtime.h>
#include <math.h>

#define NN 4096
#define INDIM 45
#define HH 44
#define NHEAD 4
#define HD 11
#define NEDGE 131072
#define CAP 128            // compaction capacity (deg ~ Poisson(32)+diag)
#define MASKW (NN / 64)
#define NPB 8              // nodes per block in proj_zero
#define RPITCH 66          // LDS reduce pitch: banks (2d+2i)%32 distinct for d<=12

__device__ __forceinline__ float wsum64(float v) {
    #pragma unroll
    for (int i = 32; i > 0; i >>= 1) v += __shfl_xor(v, i, 64);
    return v;
}
__device__ __forceinline__ float wmax64(float v) {
    #pragma unroll
    for (int i = 32; i > 0; i >>= 1) v = fmaxf(v, __shfl_xor(v, i, 64));
    return v;
}

// ---------------- Kernel 1: zero mask + fused input/QKV projection ----------------
// Q layout: [n][h][12] (pad 1), KV layout: [n][h][24] (K at +0..10, V at +12..22).
__global__ __launch_bounds__(256)
void proj_zero(const float* __restrict__ nf,
               const float* __restrict__ Wp, const float* __restrict__ bp,
               const float* __restrict__ Wq, const float* __restrict__ bq,
               const float* __restrict__ Wk, const float* __restrict__ bk,
               const float* __restrict__ Wv, const float* __restrict__ bv,
               unsigned long long* __restrict__ mask,
               float* __restrict__ Qp, float* __restrict__ KVp) {
    const int tid = threadIdx.x;
    const int gsz = gridDim.x * 256;
    for (int i = blockIdx.x * 256 + tid; i < NN * MASKW; i += gsz) mask[i] = 0ull;

    __shared__ float xs[NPB][HH];
    const int n0 = blockIdx.x * NPB;
    for (int idx = tid; idx < NPB * HH; idx += 256) {
        int nl = idx / HH, j = idx - nl * HH;
        const float* row = nf + (size_t)(n0 + nl) * INDIM;
        float a = bp[j];
        #pragma unroll
        for (int k = 0; k < INDIM; ++k) a += row[k] * Wp[k * HH + j];
        xs[nl][j] = a;
    }
    __syncthreads();
    for (int idx = tid; idx < NPB * HH; idx += 256) {
        int nl = idx / HH, j = idx - nl * HH;
        const float* row = xs[nl];
        float aq = bq[j], ak = bk[j], av = bv[j];
        #pragma unroll
        for (int k = 0; k < HH; ++k) {
            float xv = row[k];
            aq += xv * Wq[k * HH + j];
            ak += xv * Wk[k * HH + j];
            av += xv * Wv[k * HH + j];
        }
        int h = j / HD, d = j - h * HD;
        size_t nh = (size_t)(n0 + nl) * NHEAD + h;
        Qp[nh * 12 + d]       = aq;
        KVp[nh * 24 + d]      = ak;
        KVp[nh * 24 + 12 + d] = av;
    }
}

// ---------------- Kernel 2: scatter edges (diagonal folded into attn) ----------------
__global__ __launch_bounds__(256)
void build_mask(const int* __restrict__ ei, unsigned long long* __restrict__ mask) {
    int i = blockIdx.x * blockDim.x + threadIdx.x;
    if (i < NEDGE) {
        int r = ei[i];          // query
        int c = ei[NEDGE + i];  // key
        atomicOr(&mask[(size_t)r * MASKW + (c >> 6)], 1ull << (c & 63));
    }
}

// ---------------- Kernel 3: sparse attention + fused output projection ----------------
// Block = one query row, wave h = head h. Per-wave redundant mask compaction
// (no barrier; identical deterministic values). Fast path (deg<=64, ~always):
// direct softmax WITHOUT max-subtraction (scores bounded: |qk/sqrt(11)| ~<10,
// bias in [-24.5,0] -> exp can't overflow/underflow f32), and the 13 butterfly
// reductions (78 serial shuffles) are replaced by an LDS transpose-reduce:
// 12 conflict-free ds_writes, then lanes 0..11 sum one row each as 32 float2
// reads (same-wave in-order LDS pipeline, no barrier needed).
__global__ __launch_bounds__(256, 4)
void attn_out(const float* __restrict__ Qp, const float* __restrict__ KVp,
              const float* __restrict__ temporal,
              const unsigned long long* __restrict__ mask,
              const float* __restrict__ Wo, const float* __restrict__ bo,
              float* __restrict__ out) {
    const int tid = threadIdx.x;
    const int lane = tid & 63;
    const int h = tid >> 6;
    const int n = blockIdx.x;
    const float scale = 0.30151134457776363f;  // 1/sqrt(11)
    const float tbmul = 9.99990000099999f;     // 1/(0.1+1e-6)

    __shared__ int cols_s[NHEAD][CAP];
    __shared__ float red_s[NHEAD][12][RPITCH]; // [wave][d][lane]; row 11 = p
    __shared__ float att_s[HH];

    // --- per-wave redundant compaction (edges + diagonal) ---
    unsigned long long w = mask[(size_t)n * MASKW + lane];
    if (lane == (n >> 6)) w |= 1ull << (n & 63);
    int c = __popcll(w);
    int inc = c;
    #pragma unroll
    for (int i = 1; i < 64; i <<= 1) {
        int v = __shfl_up(inc, i, 64);
        if (lane >= i) inc += v;
    }
    int off = inc - c;                 // exclusive prefix
    int deg = __shfl(inc, 63, 64);
    if (deg > CAP) deg = CAP;
    while (w) {
        int b = __builtin_ctzll(w);
        w &= w - 1;
        if (off < CAP) cols_s[h][off] = lane * 64 + b;
        ++off;
    }

    const float4* qp4 = (const float4*)(Qp + ((size_t)n * NHEAD + h) * 12);
    float4 q0 = qp4[0], q1 = qp4[1], q2 = qp4[2];

    if (deg <= 64) {
        // ---- fast path: single chunk, direct (max-free) softmax ----
        const bool act = lane < deg;
        const int col = act ? cols_s[h][lane] : cols_s[h][0];
        float t = temporal[((size_t)n * NN + col) * 2];
        const float4* kv4 = (const float4*)(KVp + ((size_t)col * NHEAD + h) * 24);
        float4 a0 = kv4[0], a1 = kv4[1], a2 = kv4[2];
        float4 b0 = kv4[3], b1 = kv4[4], b2 = kv4[5];
        float s = q0.x*a0.x + q0.y*a0.y + q0.z*a0.z + q0.w*a0.w
                + q1.x*a1.x + q1.y*a1.y + q1.z*a1.z + q1.w*a1.w
                + q2.x*a2.x + q2.y*a2.y + q2.z*a2.z;
        float p = act ? __expf(s * scale - sqrtf(t * tbmul)) : 0.f;
        float vv[11] = {b0.x,b0.y,b0.z,b0.w, b1.x,b1.y,b1.z,b1.w, b2.x,b2.y,b2.z};

        // transpose-reduce via LDS (conflict-free: lane-stride-1 writes)
        float* myred = &red_s[h][0][0];
        #pragma unroll
        for (int d = 0; d < HD; ++d) myred[d * RPITCH + lane] = p * vv[d];
        myred[11 * RPITCH + lane] = p;
        // lanes 0..11 each sum one row (lanes >=12 alias row 0: broadcast, free)
        int dd = lane < 12 ? lane : 0;
        const float2* rp = (const float2*)(myred + dd * RPITCH);
        float sum = 0.f;
        #pragma unroll
        for (int i = 0; i < 32; ++i) { float2 v2 = rp[i]; sum += v2.x + v2.y; }
        float inv = 1.f / __shfl(sum, 11, 64);
        if (lane < HD) att_s[h * HD + lane] = sum * inv;
    } else {
        // ---- rare fallback (deg>64): online softmax, butterfly merge ----
        float mcur = -INFINITY, lsum = 0.f, oacc[HD];
        #pragma unroll
        for (int d = 0; d < HD; ++d) oacc[d] = 0.f;
        for (int base = 0; base < deg; base += 64) {
            const int jj = base + lane;
            const bool act = jj < deg;
            const int col = act ? cols_s[h][jj] : 0;
            float t = temporal[((size_t)n * NN + col) * 2];
            const float4* kv4 = (const float4*)(KVp + ((size_t)col * NHEAD + h) * 24);
            float4 a0 = kv4[0], a1 = kv4[1], a2 = kv4[2];
            float4 b0 = kv4[3], b1 = kv4[4], b2 = kv4[5];
            float s = q0.x*a0.x + q0.y*a0.y + q0.z*a0.z + q0.w*a0.w
                    + q1.x*a1.x + q1.y*a1.y + q1.z*a1.z + q1.w*a1.w
                    + q2.x*a2.x + q2.y*a2.y + q2.z*a2.z;
            float vv[12] = {b0.x,b0.y,b0.z,b0.w, b1.x,b1.y,b1.z,b1.w, b2.x,b2.y,b2.z,b2.w};
            if (act) {
                s = s * scale - sqrtf(t * tbmul);
                if (s > mcur) {
                    float f = __expf(mcur - s);
                    lsum *= f;
                    #pragma unroll
                    for (int d = 0; d < HD; ++d) oacc[d] *= f;
                    mcur = s;
                }
                float p = __expf(s - mcur);
                lsum += p;
                #pragma unroll
                for (int d = 0; d < HD; ++d) oacc[d] += p * vv[d];
            }
        }
        float M = wmax64(mcur);
        float sc = (mcur == -INFINITY) ? 0.f : __expf(mcur - M);
        float L = wsum64(lsum * sc);
        float inv = 1.f / L;
        #pragma unroll
        for (int d = 0; d < HD; ++d) {
            float o = wsum64(oacc[d] * sc);
            if (lane == d) att_s[h * HD + d] = o * inv;
        }
    }
    __syncthreads();

    if (tid < HH) {
        float a = bo[tid];
        #pragma unroll
        for (int k = 0; k < HH; ++k) a += att_s[k] * Wo[k * HH + tid];
        out[(size_t)n * HH + tid] = a;
    }
}

extern "C" void kernel_launch(void* const* d_in, const int* in_sizes, int n_in,
                              void* d_out, int out_size, void* d_ws, size_t ws_size,
                              hipStream_t stream) {
    const float* nf       = (const float*)d_in[0];
    const int*   ei       = (const int*)d_in[1];
    const float* temporal = (const float*)d_in[2];
    const float* Wp = (const float*)d_in[3];
    const float* bp = (const float*)d_in[4];
    const float* Wq = (const float*)d_in[5];
    const float* bq = (const float*)d_in[6];
    const float* Wk = (const float*)d_in[7];
    const float* bk = (const float*)d_in[8];
    const float* Wv = (const float*)d_in[9];
    const float* bv = (const float*)d_in[10];
    const float* Wo = (const float*)d_in[11];
    const float* bo = (const float*)d_in[12];
    float* outp = (float*)d_out;

    char* ws = (char*)d_ws;
    unsigned long long* mask = (unsigned long long*)ws;        // 2 MB
    float* Qp  = (float*)(ws + (2u << 20));                    // NN*4*12 floats
    float* KVp = Qp + (size_t)NN * NHEAD * 12;                 // NN*4*24 floats

    proj_zero<<<NN / NPB, 256, 0, stream>>>(nf, Wp, bp, Wq, bq, Wk, bk, Wv, bv,
                                            mask, Qp, KVp);
    build_mask<<<(NEDGE + 255) / 256, 256, 0, stream>>>(ei, mask);
    attn_out<<<NN, 256, 0, stream>>>(Qp, KVp, temporal, mask, Wo, bo, outp);
}

// Round 12
// 33.634 us; speedup vs baseline: 1.5238x; 1.1319x over previous
//
#include <hip/hip_runtime.h>
#include <math.h>

#define NN 4096
#define INDIM 45
#define HH 44
#define NHEAD 4
#define HD 11
#define NEDGE 131072
#define CAP 128            // compaction capacity (deg ~ Poisson(32)+diag)
#define MASKW (NN / 64)
#define NPB 8              // nodes per block in proj_zero
#define RPITCH 66          // LDS reduce pitch: banks (2d+2i)%32 distinct for d<=12

typedef unsigned short ushort_t;

__device__ __forceinline__ float wsum64(float v) {
    #pragma unroll
    for (int i = 32; i > 0; i >>= 1) v += __shfl_xor(v, i, 64);
    return v;
}
__device__ __forceinline__ float wmax64(float v) {
    #pragma unroll
    for (int i = 32; i > 0; i >>= 1) v = fmaxf(v, __shfl_xor(v, i, 64));
    return v;
}
// bf16 (RNE) pack/unpack via bit ops
__device__ __forceinline__ ushort_t f2bf(float x) {
    unsigned u = __float_as_uint(x);
    u += 0x7FFFu + ((u >> 16) & 1u);
    return (ushort_t)(u >> 16);
}
__device__ __forceinline__ float bfl(unsigned u) { return __uint_as_float(u << 16); }
__device__ __forceinline__ float bfh(unsigned u) { return __uint_as_float(u & 0xFFFF0000u); }

// ---------------- Kernel 1: zero mask + fused input/QKV projection ----------------
// Q layout: [n][h][12] f32 (pad 1). KV layout: [n][h][24] bf16 — K in slots 0..10,
// V in 12..22, pads at 11/23 never read. 48B per (n,h), 16B-aligned -> 3 uint4 loads.
__global__ __launch_bounds__(256)
void proj_zero(const float* __restrict__ nf,
               const float* __restrict__ Wp, const float* __restrict__ bp,
               const float* __restrict__ Wq, const float* __restrict__ bq,
               const float* __restrict__ Wk, const float* __restrict__ bk,
               const float* __restrict__ Wv, const float* __restrict__ bv,
               unsigned long long* __restrict__ mask,
               float* __restrict__ Qp, ushort_t* __restrict__ KVb) {
    const int tid = threadIdx.x;
    const int gsz = gridDim.x * 256;
    for (int i = blockIdx.x * 256 + tid; i < NN * MASKW; i += gsz) mask[i] = 0ull;

    __shared__ float xs[NPB][HH];
    const int n0 = blockIdx.x * NPB;
    for (int idx = tid; idx < NPB * HH; idx += 256) {
        int nl = idx / HH, j = idx - nl * HH;
        const float* row = nf + (size_t)(n0 + nl) * INDIM;
        float a = bp[j];
        #pragma unroll
        for (int k = 0; k < INDIM; ++k) a += row[k] * Wp[k * HH + j];
        xs[nl][j] = a;
    }
    __syncthreads();
    for (int idx = tid; idx < NPB * HH; idx += 256) {
        int nl = idx / HH, j = idx - nl * HH;
        const float* row = xs[nl];
        float aq = bq[j], ak = bk[j], av = bv[j];
        #pragma unroll
        for (int k = 0; k < HH; ++k) {
            float xv = row[k];
            aq += xv * Wq[k * HH + j];
            ak += xv * Wk[k * HH + j];
            av += xv * Wv[k * HH + j];
        }
        int h = j / HD, d = j - h * HD;
        size_t nh = (size_t)(n0 + nl) * NHEAD + h;
        Qp[nh * 12 + d]       = aq;
        KVb[nh * 24 + d]      = f2bf(ak);
        KVb[nh * 24 + 12 + d] = f2bf(av);
    }
}

// ---------------- Kernel 2: scatter edges (diagonal folded into attn) ----------------
__global__ __launch_bounds__(256)
void build_mask(const int* __restrict__ ei, unsigned long long* __restrict__ mask) {
    int i = blockIdx.x * blockDim.x + threadIdx.x;
    if (i < NEDGE) {
        int r = ei[i];          // query
        int c = ei[NEDGE + i];  // key
        atomicOr(&mask[(size_t)r * MASKW + (c >> 6)], 1ull << (c & 63));
    }
}

// ---------------- Kernel 3: sparse attention + fused output projection ----------------
// Block = one query row, wave h = head h. Per-wave redundant mask compaction
// (no barrier; deterministic). Fast path (deg<=64, ~always): direct max-free
// softmax (scores bounded), LDS transpose-reduce epilogue. KV fetched as
// 3 divergent uint4 loads per (col,head) — bf16-packed, halving the TA/line
// traffic vs 6 float4 f32 loads (the round-11 bottleneck).
__global__ __launch_bounds__(256, 4)
void attn_out(const float* __restrict__ Qp, const ushort_t* __restrict__ KVb,
              const float* __restrict__ temporal,
              const unsigned long long* __restrict__ mask,
              const float* __restrict__ Wo, const float* __restrict__ bo,
              float* __restrict__ out) {
    const int tid = threadIdx.x;
    const int lane = tid & 63;
    const int h = tid >> 6;
    const int n = blockIdx.x;
    const float scale = 0.30151134457776363f;  // 1/sqrt(11)
    const float tbmul = 9.99990000099999f;     // 1/(0.1+1e-6)

    __shared__ int cols_s[NHEAD][CAP];
    __shared__ float red_s[NHEAD][12][RPITCH]; // [wave][d][lane]; row 11 = p
    __shared__ float att_s[HH];

    // --- per-wave redundant compaction (edges + diagonal) ---
    unsigned long long w = mask[(size_t)n * MASKW + lane];
    if (lane == (n >> 6)) w |= 1ull << (n & 63);
    int c = __popcll(w);
    int inc = c;
    #pragma unroll
    for (int i = 1; i < 64; i <<= 1) {
        int v = __shfl_up(inc, i, 64);
        if (lane >= i) inc += v;
    }
    int off = inc - c;                 // exclusive prefix
    int deg = __shfl(inc, 63, 64);
    if (deg > CAP) deg = CAP;
    while (w) {
        int b = __builtin_ctzll(w);
        w &= w - 1;
        if (off < CAP) cols_s[h][off] = lane * 64 + b;
        ++off;
    }

    const float4* qp4 = (const float4*)(Qp + ((size_t)n * NHEAD + h) * 12);
    float4 q0 = qp4[0], q1 = qp4[1], q2 = qp4[2];

    if (deg <= 64) {
        // ---- fast path: single chunk, direct (max-free) softmax ----
        const bool act = lane < deg;
        const int col = act ? cols_s[h][lane] : cols_s[h][0];
        float t = temporal[((size_t)n * NN + col) * 2];
        const uint4* kv4 = (const uint4*)(KVb + (size_t)(col * NHEAD + h) * 24);
        uint4 A = kv4[0], B = kv4[1], C = kv4[2];
        float s = q0.x*bfl(A.x) + q0.y*bfh(A.x) + q0.z*bfl(A.y) + q0.w*bfh(A.y)
                + q1.x*bfl(A.z) + q1.y*bfh(A.z) + q1.z*bfl(A.w) + q1.w*bfh(A.w)
                + q2.x*bfl(B.x) + q2.y*bfh(B.x) + q2.z*bfl(B.y);
        float p = act ? __expf(s * scale - sqrtf(t * tbmul)) : 0.f;
        float vv[11] = { bfl(B.z), bfh(B.z), bfl(B.w), bfh(B.w),
                         bfl(C.x), bfh(C.x), bfl(C.y), bfh(C.y),
                         bfl(C.z), bfh(C.z), bfl(C.w) };

        // transpose-reduce via LDS (conflict-free: lane-stride-1 writes)
        float* myred = &red_s[h][0][0];
        #pragma unroll
        for (int d = 0; d < HD; ++d) myred[d * RPITCH + lane] = p * vv[d];
        myred[11 * RPITCH + lane] = p;
        // lanes 0..11 each sum one row (lanes >=12 alias row 0: broadcast, free)
        int dd = lane < 12 ? lane : 0;
        const float2* rp = (const float2*)(myred + dd * RPITCH);
        float sum = 0.f;
        #pragma unroll
        for (int i = 0; i < 32; ++i) { float2 v2 = rp[i]; sum += v2.x + v2.y; }
        float inv = 1.f / __shfl(sum, 11, 64);
        if (lane < HD) att_s[h * HD + lane] = sum * inv;
    } else {
        // ---- rare fallback (deg>64): online softmax, butterfly merge ----
        float mcur = -INFINITY, lsum = 0.f, oacc[HD];
        #pragma unroll
        for (int d = 0; d < HD; ++d) oacc[d] = 0.f;
        for (int base = 0; base < deg; base += 64) {
            const int jj = base + lane;
            const bool act = jj < deg;
            const int col = act ? cols_s[h][jj] : 0;
            float t = temporal[((size_t)n * NN + col) * 2];
            const uint4* kv4 = (const uint4*)(KVb + (size_t)(col * NHEAD + h) * 24);
            uint4 A = kv4[0], B = kv4[1], C = kv4[2];
            float s = q0.x*bfl(A.x) + q0.y*bfh(A.x) + q0.z*bfl(A.y) + q0.w*bfh(A.y)
                    + q1.x*bfl(A.z) + q1.y*bfh(A.z) + q1.z*bfl(A.w) + q1.w*bfh(A.w)
                    + q2.x*bfl(B.x) + q2.y*bfh(B.x) + q2.z*bfl(B.y);
            float vv[11] = { bfl(B.z), bfh(B.z), bfl(B.w), bfh(B.w),
                             bfl(C.x), bfh(C.x), bfl(C.y), bfh(C.y),
                             bfl(C.z), bfh(C.z), bfl(C.w) };
            if (act) {
                s = s * scale - sqrtf(t * tbmul);
                if (s > mcur) {
                    float f = __expf(mcur - s);
                    lsum *= f;
                    #pragma unroll
                    for (int d = 0; d < HD; ++d) oacc[d] *= f;
                    mcur = s;
                }
                float p = __expf(s - mcur);
                lsum += p;
                #pragma unroll
                for (int d = 0; d < HD; ++d) oacc[d] += p * vv[d];
            }
        }
        float M = wmax64(mcur);
        float sc = (mcur == -INFINITY) ? 0.f : __expf(mcur - M);
        float L = wsum64(lsum * sc);
        float inv = 1.f / L;
        #pragma unroll
        for (int d = 0; d < HD; ++d) {
            float o = wsum64(oacc[d] * sc);
            if (lane == d) att_s[h * HD + d] = o * inv;
        }
    }
    __syncthreads();

    if (tid < HH) {
        float a = bo[tid];
        #pragma unroll
        for (int k = 0; k < HH; ++k) a += att_s[k] * Wo[k * HH + tid];
        out[(size_t)n * HH + tid] = a;
    }
}

extern "C" void kernel_launch(void* const* d_in, const int* in_sizes, int n_in,
                              void* d_out, int out_size, void* d_ws, size_t ws_size,
                              hipStream_t stream) {
    const float* nf       = (const float*)d_in[0];
    const int*   ei       = (const int*)d_in[1];
    const float* temporal = (const float*)d_in[2];
    const float* Wp = (const float*)d_in[3];
    const float* bp = (const float*)d_in[4];
    const float* Wq = (const float*)d_in[5];
    const float* bq = (const float*)d_in[6];
    const float* Wk = (const float*)d_in[7];
    const float* bk = (const float*)d_in[8];
    const float* Wv = (const float*)d_in[9];
    const float* bv = (const float*)d_in[10];
    const float* Wo = (const float*)d_in[11];
    const float* bo = (const float*)d_in[12];
    float* outp = (float*)d_out;

    char* ws = (char*)d_ws;
    unsigned long long* mask = (unsigned long long*)ws;        // 2 MB
    float*    Qp  = (float*)(ws + (2u << 20));                 // NN*4*12 f32
    ushort_t* KVb = (ushort_t*)(Qp + (size_t)NN * NHEAD * 12); // NN*4*24 bf16

    proj_zero<<<NN / NPB, 256, 0, stream>>>(nf, Wp, bp, Wq, bq, Wk, bk, Wv, bv,
                                            mask, Qp, KVb);
    build_mask<<<(NEDGE + 255) / 256, 256, 0, stream>>>(ei, mask);
    attn_out<<<NN, 256, 0, stream>>>(Qp, KVb, temporal, mask, Wo, bo, outp);
}